// Round 22
// baseline (101.698 us; speedup 1.0000x reference)
//
#include <hip/hip_runtime.h>

#define DIM_ 1024
#define HEADS_ 16
#define HD_ 64
#define T_ 2048
#define BATCH_ 2
#define QKVN_ 3072

typedef unsigned short u16;
typedef unsigned int u32;
typedef float f32x4 __attribute__((ext_vector_type(4)));
typedef float f32x16 __attribute__((ext_vector_type(16)));
typedef short s16x8 __attribute__((ext_vector_type(8)));
typedef unsigned short u16x4 __attribute__((ext_vector_type(4)));

__device__ __forceinline__ u16 f2bf(float f) {
  unsigned u = __float_as_uint(f);
  u += 0x7fffu + ((u >> 16) & 1u);
  return (u16)(u >> 16);
}

__device__ __forceinline__ float fexp2(float x) {
  float r;
  asm("v_exp_f32 %0, %1" : "=v"(r) : "v"(x));
  return r;
}

__device__ __forceinline__ float fmax3(float a, float b, float c) {
  float r;
  asm("v_max3_f32 %0, %1, %2, %3" : "=v"(r) : "v"(a), "v"(b), "v"(c));
  return r;
}

__device__ __forceinline__ u32 cvtpk(float a, float b) {
  u32 r;
  asm("v_cvt_pk_bf16_f32 %0, %1, %2" : "=v"(r) : "v"(a), "v"(b));
  return r;
}

// ---------------- fused fp32 -> bf16 conversion (x | w_qkv | w_out) ----------------
__global__ __launch_bounds__(256) void cvt_all(const float* __restrict__ x,
                                               const float* __restrict__ wqkv,
                                               const float* __restrict__ wout,
                                               u16* __restrict__ outbase) {
  int i = blockIdx.x * 256 + threadIdx.x;   // [0, 2097152)
  const float4* src;
  int off;
  if (i < 1048576) { src = (const float4*)x; off = i; }
  else if (i < 1835008) { src = (const float4*)wqkv; off = i - 1048576; }
  else { src = (const float4*)wout; off = i - 1835008; }
  float4 v = src[off];
  u16x4 o;
  o.x = f2bf(v.x); o.y = f2bf(v.y); o.z = f2bf(v.z); o.w = f2bf(v.w);
  reinterpret_cast<u16x4*>(outbase)[i] = o;
}

// ---------------- async global->LDS helper ----------------
__device__ __forceinline__ void gld_lds16(const void* g, void* l) {
  auto gp = (__attribute__((address_space(1))) char*)(unsigned long long)g;
  auto lp = (__attribute__((address_space(3))) char*)(unsigned int)(unsigned long long)l;
  __builtin_amdgcn_global_load_lds(gp, lp, 16, 0, 0);
}

// ---------------- GEMM, BK=64, double-buffered one-barrier pipeline (R21) ----------
template <int MODE>
__global__ __launch_bounds__(256) void gemm1(const u16* __restrict__ A,
                                             const u16* __restrict__ B,
                                             void* __restrict__ Cv,
                                             u16* __restrict__ vto) {
  constexpr int K = 1024;
  constexpr int NN = (MODE == 1) ? 1024 : QKVN_;
  constexpr int NT = (MODE == 1) ? 8 : 24;
  constexpr int CPX = (MODE == 1) ? 32 : 96;
  __shared__ __align__(16) u16 smem[32768];   // 64 KB
  char* const smb = (char*)smem;
  const int bid = blockIdx.x;
  const int wk = (bid & 7) * CPX + (bid >> 3);
  const int mt = wk / NT, nt = wk % NT;
  const int tid = threadIdx.x;
  const int lane = tid & 63;
  const int w = tid >> 6;
  const int wr = w >> 1, wc = w & 1;
  const int lrow = lane & 15, kg = lane >> 4;
  const u16* Ag = A + (size_t)(mt * 128) * K;
  const u16* Bg = B + (size_t)(nt * 128) * K;

  f32x4 acc[4][4];
#pragma unroll
  for (int i = 0; i < 4; ++i)
#pragma unroll
    for (int j = 0; j < 4; ++j) {
      f32x4 z = {0.f, 0.f, 0.f, 0.f};
      acc[i][j] = z;
    }

  const int srow = tid >> 3;
  const int scol = 8 * ((tid & 7) ^ ((tid >> 3) & 7));
  const int ldsw = (tid & ~63) * 16;

  int aoff[4][2], boff[4][2];
#pragma unroll
  for (int mf = 0; mf < 4; ++mf)
#pragma unroll
    for (int ks = 0; ks < 2; ++ks) {
      aoff[mf][ks] = (wr * 64 + mf * 16 + lrow) * 128 + (((ks * 4 + kg) ^ (lrow & 7)) << 4);
      boff[mf][ks] = (wc * 64 + mf * 16 + lrow) * 128 + (((ks * 4 + kg) ^ (lrow & 7)) << 4);
    }

#pragma unroll
  for (int c = 0; c < 4; ++c) {
    gld_lds16(Ag + (size_t)(c * 32 + srow) * K + scol, smb + c * 4096 + ldsw);
    gld_lds16(Bg + (size_t)(c * 32 + srow) * K + scol, smb + 32768 + c * 4096 + ldsw);
  }

  int cur = 0;
  for (int k0 = 0; k0 < K; k0 += 64) {
    __syncthreads();
    if (k0 + 64 < K) {
      const int nb = (cur ^ 1) * 16384;
#pragma unroll
      for (int c = 0; c < 4; ++c) {
        gld_lds16(Ag + (size_t)(c * 32 + srow) * K + k0 + 64 + scol,
                  smb + nb + c * 4096 + ldsw);
        gld_lds16(Bg + (size_t)(c * 32 + srow) * K + k0 + 64 + scol,
                  smb + 32768 + nb + c * 4096 + ldsw);
      }
    }
    const char* Ac = smb + cur * 16384;
    const char* Bc = smb + 32768 + cur * 16384;
#pragma unroll
    for (int ks = 0; ks < 2; ++ks) {
      s16x8 a[4], b[4];
#pragma unroll
      for (int mf = 0; mf < 4; ++mf)
        a[mf] = *(const s16x8*)(Ac + aoff[mf][ks]);
#pragma unroll
      for (int nf = 0; nf < 4; ++nf)
        b[nf] = *(const s16x8*)(Bc + boff[nf][ks]);
#pragma unroll
      for (int mf = 0; mf < 4; ++mf)
#pragma unroll
        for (int nf = 0; nf < 4; ++nf)
          acc[mf][nf] = __builtin_amdgcn_mfma_f32_16x16x32_bf16(a[mf], b[nf], acc[mf][nf], 0, 0, 0);
    }
    cur ^= 1;
  }

  if (MODE == 1) {
    float* C = (float*)Cv;
#pragma unroll
    for (int mf = 0; mf < 4; ++mf)
#pragma unroll
      for (int nf = 0; nf < 4; ++nf)
#pragma unroll
        for (int j = 0; j < 4; ++j) {
          int r = mt * 128 + wr * 64 + mf * 16 + 4 * kg + j;
          int c = nt * 128 + wc * 64 + nf * 16 + lrow;
          C[(size_t)r * NN + c] = acc[mf][nf][j];
        }
  } else if (nt < 16) {
    u16* qkvo = (u16*)Cv;
#pragma unroll
    for (int mf = 0; mf < 4; ++mf)
#pragma unroll
      for (int nf = 0; nf < 4; ++nf)
#pragma unroll
        for (int j = 0; j < 4; ++j) {
          int r = mt * 128 + wr * 64 + mf * 16 + 4 * kg + j;
          int c = nt * 128 + wc * 64 + nf * 16 + lrow;
          qkvo[(size_t)r * QKVN_ + c] = f2bf(acc[mf][nf][j]);
        }
  } else {
    const int c16 = tid >> 4, chunk = tid & 15;
    const int bb = mt >> 4;
    const int tb = (mt & 15) * 128 + chunk * 8;
#pragma unroll
    for (int p = 0; p < 2; ++p) {
      __syncthreads();
      if (wc == p) {
#pragma unroll
        for (int mf = 0; mf < 4; ++mf)
#pragma unroll
          for (int nf = 0; nf < 4; ++nf) {
            const int cl = nf * 16 + lrow;
            const int rl = wr * 64 + mf * 16 + 4 * kg;
            u16x4 pk;
            pk.x = f2bf(acc[mf][nf][0]); pk.y = f2bf(acc[mf][nf][1]);
            pk.z = f2bf(acc[mf][nf][2]); pk.w = f2bf(acc[mf][nf][3]);
            *(u16x4*)&smem[cl * 136 + rl] = pk;
          }
      }
      __syncthreads();
#pragma unroll
      for (int pp = 0; pp < 4; ++pp) {
        const int cl = pp * 16 + c16;
        const int cg = nt * 128 + p * 64 + cl;
        const int hV = (cg >> 6) & 15, d = cg & 63;
        const s16x8 v = *(const s16x8*)&smem[cl * 136 + chunk * 8];
        *(s16x8*)(vto + ((size_t)((bb * 16 + hV) * 64 + d)) * T_ + tb) = v;
      }
    }
  }
}

// ---------------- causal flash attention (fused pair, shared KV staging, 8 waves) ------
// 512 blocks (16 pairs x 32 bh, XCD bh-clustered), 512 threads = 8 waves:
// w = (qhalf, qw, kvg). qhalf 0 -> jt=31-pr (big), 1 -> jt=pr (small; kv range is a
// PREFIX of big's, so one staging stream serves both). K/V double-buffered 64 KB,
// one barrier/round, reg-staged write-late (R15-proven core). Rounds = ceil((32-pr)/2).
__global__ __launch_bounds__(512) void attn_fwd(const u16* __restrict__ qkv,
                                                const u16* __restrict__ vt,
                                                u16* __restrict__ o) {
  const int gid = blockIdx.x;
  const int gq = gid >> 3;
  const int bh = (gid & 7) * 4 + (gq >> 4);
  const int pr = gq & 15;              // 0..15
  const int b = bh >> 4, h = bh & 15;
  const int tid = threadIdx.x;
  const int lane = tid & 63;
  const int w8 = tid >> 6;             // 0..7
  const int qhalf = w8 >> 2;           // 0 = big tile, 1 = small tile
  const int qw = (w8 >> 1) & 1;        // 32-row subwave within the 64-row tile
  const int kvg = w8 & 1;              // kv parity
  const int l31 = lane & 31, hi = lane >> 5;

  const int jt = qhalf ? pr : (31 - pr);
  const int nt = jt + 1;               // this wave's kv-tile count
  const int ntmax = 32 - pr;           // staging covers the big tile's range
  const int nrt = (ntmax + 1) >> 1;
  const int qrow0 = 64 * jt + 32 * qw;

  // K: smem + buf*16384 + par*8192 ; V: +32768 same
  __shared__ __align__(16) char smem[65536];

  // staging: 512 threads -> one 16B chunk per tile; row_s 0..63
  const int row_s = tid >> 3, slot_s = tid & 7;
  const u16* Kbase = qkv + (size_t)(b * T_) * QKVN_ + 1024 + h * 64;
  const u16* Vbase = vt + (size_t)(bh * 64) * T_;
  const u16* Kg = Kbase + (size_t)row_s * QKVN_ + slot_s * 8;   // + t*64*QKVN_
  const u16* Vg = Vbase + (size_t)row_s * T_ + slot_s * 8;      // + t*64
  const int dst = row_s * 128 + ((slot_s ^ (row_s & 7)) << 4);

  const int rbyte = l31 * 128;
  const int xsw = l31 & 7;
  const float CEXP = 0.18033688011112042f;  // (1/8) * log2(e)

  // Q fragments: lane (l31,hi) holds Q[qrow0+l31][16*ksl + 8*hi .. +8]
  s16x8 qf[4];
  {
    const u16* qp = qkv + (size_t)(b * T_ + qrow0 + l31) * QKVN_ + h * 64 + 8 * hi;
#pragma unroll
    for (int ksl = 0; ksl < 4; ++ksl)
      qf[ksl] = *(const s16x8*)(qp + 16 * ksl);
  }

  f32x16 o0v, o1v;
#pragma unroll
  for (int r = 0; r < 16; ++r) { o0v[r] = 0.f; o1v[r] = 0.f; }
  float mrun = -__builtin_inff(), lrun = 0.0f;

  // prologue: stage tiles 0 (par0) and 1 (par1) into buf 0 (ntmax >= 17 always)
  *(s16x8*)(smem + dst)                 = *(const s16x8*)Kg;
  *(s16x8*)(smem + 32768 + dst)         = *(const s16x8*)Vg;
  *(s16x8*)(smem + 8192 + dst)          = *(const s16x8*)(Kg + (size_t)64 * QKVN_);
  *(s16x8*)(smem + 32768 + 8192 + dst)  = *(const s16x8*)(Vg + 64);

  int cur = 0;
  for (int r = 0; r < nrt; ++r) {
    const int t = 2 * r + kvg;
    const bool pe = (2 * r + 2 < ntmax), po = (2 * r + 3 < ntmax);
    s16x8 ke, ve, ko, vo;
    if (pe) {                         // issue next-round loads early
      ke = *(const s16x8*)(Kg + (size_t)(2 * r + 2) * 64 * QKVN_);
      ve = *(const s16x8*)(Vg + (2 * r + 2) * 64);
    }
    if (po) {
      ko = *(const s16x8*)(Kg + (size_t)(2 * r + 3) * 64 * QKVN_);
      vo = *(const s16x8*)(Vg + (2 * r + 3) * 64);
    }
    __syncthreads();                  // publishes buf cur; prior-round reads done

    if (t < nt) {
      const char* Kc = smem + cur * 16384 + kvg * 8192;
      const char* Vc = smem + 32768 + cur * 16384 + kvg * 8192;
      const bool isdiag = (t == nt - 1);
      const bool two = !(isdiag && qw == 0);

      // ---- QK^T (swapped): lane holds q = qrow0+l31 ----
      f32x16 s0v, s1v;
#pragma unroll
      for (int rr = 0; rr < 16; ++rr) { s0v[rr] = 0.f; s1v[rr] = 0.f; }
      __builtin_amdgcn_s_setprio(1);
#pragma unroll
      for (int ksl = 0; ksl < 4; ++ksl) {
        const s16x8 kf = *(const s16x8*)(Kc + rbyte + (((2 * ksl + hi) ^ xsw) << 4));
        s0v = __builtin_amdgcn_mfma_f32_32x32x16_bf16(kf, qf[ksl], s0v, 0, 0, 0);
      }
      if (two) {
#pragma unroll
        for (int ksl = 0; ksl < 4; ++ksl) {
          const s16x8 kf = *(const s16x8*)(Kc + 4096 + rbyte + (((2 * ksl + hi) ^ xsw) << 4));
          s1v = __builtin_amdgcn_mfma_f32_32x32x16_bf16(kf, qf[ksl], s1v, 0, 0, 0);
        }
      }
      __builtin_amdgcn_s_setprio(0);

      // ---- causal mask (diagonal tile only) ----
      if (isdiag) {
        const int thr = 32 * qw + l31;
#pragma unroll
        for (int rr = 0; rr < 16; ++rr) {
          const int kvl = 4 * hi + (rr & 3) + 8 * (rr >> 2);
          if (kvl > thr) s0v[rr] = -__builtin_inff();
          if (two && kvl + 32 > thr) s1v[rr] = -__builtin_inff();
        }
      }

      // ---- online softmax, per-lane (v_max3 tree) ----
      float mloc = fmax3(s0v[0], s0v[1], s0v[2]);
#pragma unroll
      for (int rr = 3; rr < 15; rr += 2) mloc = fmax3(mloc, s0v[rr], s0v[rr + 1]);
      mloc = fmaxf(mloc, s0v[15]);
      if (two) {
        mloc = fmax3(mloc, s1v[0], s1v[1]);
#pragma unroll
        for (int rr = 2; rr < 16; rr += 2) mloc = fmax3(mloc, s1v[rr], s1v[rr + 1]);
      }
      mloc = fmaxf(mloc, __shfl_xor(mloc, 32));

      const bool needfull = !((mloc - mrun) * CEXP <= 8.0f);
      if (__any(needfull)) {
        const float newm = fmaxf(mrun, mloc);
        const float sc = fexp2((mrun - newm) * CEXP);
        mrun = newm;
        lrun *= sc;
        o0v *= sc;
        o1v *= sc;
      }
      const float msc = mrun * CEXP;

      float rs = 0.0f;
      u32 pd0[8], pd1[8];
#pragma unroll
      for (int ri = 0; ri < 8; ++ri) {
        const float p0 = fexp2(__builtin_fmaf(s0v[2 * ri], CEXP, -msc));
        const float p1 = fexp2(__builtin_fmaf(s0v[2 * ri + 1], CEXP, -msc));
        rs += p0 + p1;
        pd0[ri] = cvtpk(p0, p1);
      }
      if (two) {
#pragma unroll
        for (int ri = 0; ri < 8; ++ri) {
          const float p0 = fexp2(__builtin_fmaf(s1v[2 * ri], CEXP, -msc));
          const float p1 = fexp2(__builtin_fmaf(s1v[2 * ri + 1], CEXP, -msc));
          rs += p0 + p1;
          pd1[ri] = cvtpk(p0, p1);
        }
      }
      rs += __shfl_xor(rs, 32);
      lrun += rs;

      // ---- PV: rebuild B-fragments in-register, accumulate O^T ----
      __builtin_amdgcn_s_setprio(1);
#pragma unroll
      for (int kk = 0; kk < 4; ++kk) {
        if (kk >= 2 && !two) break;
        u32 x0, y0, x1, y1;
        if (kk == 0)      { x0 = pd0[0]; y0 = pd0[2]; x1 = pd0[1]; y1 = pd0[3]; }
        else if (kk == 1) { x0 = pd0[4]; y0 = pd0[6]; x1 = pd0[5]; y1 = pd0[7]; }
        else if (kk == 2) { x0 = pd1[0]; y0 = pd1[2]; x1 = pd1[1]; y1 = pd1[3]; }
        else              { x0 = pd1[4]; y0 = pd1[6]; x1 = pd1[5]; y1 = pd1[7]; }
        asm volatile("v_permlane32_swap_b32 %0, %1" : "+v"(x0), "+v"(y0));
        asm volatile("v_permlane32_swap_b32 %0, %1" : "+v"(x1), "+v"(y1));
        u32 pw[4] = {x0, x1, y0, y1};
        const s16x8 pf = *(const s16x8*)pw;
        const s16x8 vf0 = *(const s16x8*)(Vc + rbyte + (((2 * kk + hi) ^ xsw) << 4));
        const s16x8 vf1 = *(const s16x8*)(Vc + 4096 + rbyte + (((2 * kk + hi) ^ xsw) << 4));
        o0v = __builtin_amdgcn_mfma_f32_32x32x16_bf16(vf0, pf, o0v, 0, 0, 0);
        o1v = __builtin_amdgcn_mfma_f32_32x32x16_bf16(vf1, pf, o1v, 0, 0, 0);
      }
      __builtin_amdgcn_s_setprio(0);
    }

    if (pe) {                         // write-late into the other buffer set
      const int nb = (cur ^ 1) * 16384;
      *(s16x8*)(smem + nb + dst)         = ke;
      *(s16x8*)(smem + 32768 + nb + dst) = ve;
    }
    if (po) {
      const int nb = (cur ^ 1) * 16384 + 8192;
      *(s16x8*)(smem + nb + dst)         = ko;
      *(s16x8*)(smem + 32768 + nb + dst) = vo;
    }
    cur ^= 1;
  }

  // ---- merge kv-parity partials (reuse LDS), write O ----
  __syncthreads();   // all waves done reading K/V LDS before overlay
  const int qidx = qhalf * 2 + qw;                 // 0..3
  float* Om = (float*)smem + qidx * 2048;          // 32 x 64 f32 per qidx (32 KB total)
  float* Mf = (float*)(smem + 32768) + qidx * 64;
  float* Lf = (float*)(smem + 33792) + qidx * 64;
  if (kvg == 1) {
#pragma unroll
    for (int rr = 0; rr < 16; ++rr) {
      Om[rr * 64 + lane] = o0v[rr];
      Om[(16 + rr) * 64 + lane] = o1v[rr];
    }
    Mf[lane] = mrun;
    Lf[lane] = lrun;
  }
  __syncthreads();
  if (kvg == 0) {
    const float mA = Mf[lane];
    const float lA = Lf[lane];
    const float m2 = fmaxf(mrun, mA);
    const float sB = fexp2((mrun - m2) * CEXP);
    const float sA = fexp2((mA - m2) * CEXP);
    const float linv = 1.0f / (lrun * sB + lA * sA);
    u16* orow = o + (size_t)(b * T_ + qrow0 + l31) * DIM_ + h * 64;
#pragma unroll
    for (int ri = 0; ri < 8; ++ri) {
      const int dbase0 = 4 * hi + 8 * (ri >> 1) + 2 * (ri & 1);
      const float a0 = (o0v[2 * ri] * sB + Om[(2 * ri) * 64 + lane] * sA) * linv;
      const float a1 = (o0v[2 * ri + 1] * sB + Om[(2 * ri + 1) * 64 + lane] * sA) * linv;
      const float c0 = (o1v[2 * ri] * sB + Om[(16 + 2 * ri) * 64 + lane] * sA) * linv;
      const float c1 = (o1v[2 * ri + 1] * sB + Om[(16 + 2 * ri + 1) * 64 + lane] * sA) * linv;
      *(u32*)(orow + dbase0) = cvtpk(a0, a1);
      *(u32*)(orow + 32 + dbase0) = cvtpk(c0, c1);
    }
  }
}

// ---------------- launch ----------------
extern "C" void kernel_launch(void* const* d_in, const int* in_sizes, int n_in,
                              void* d_out, int out_size, void* d_ws, size_t ws_size,
                              hipStream_t stream) {
  const float* x = (const float*)d_in[0];
  const float* w_qkv = (const float*)d_in[1];
  const float* w_out = (const float*)d_in[2];
  char* ws = (char*)d_ws;
  u16* xb    = (u16*)(ws + 0);          // 8,388,608
  u16* wqkvb = (u16*)(ws + 8388608);    // 6,291,456
  u16* woutb = (u16*)(ws + 14680064);   // 2,097,152
  u16* qkvb  = (u16*)(ws + 16777216);   // 25,165,824 (V third unused)
  u16* vtb   = (u16*)(ws + 41943040);   // 8,388,608
  u16* attno = (u16*)(ws + 50331648);   // 8,388,608

  cvt_all<<<8192, 256, 0, stream>>>(x, w_qkv, w_out, xb);
  gemm1<2><<<768, 256, 0, stream>>>(xb, wqkvb, qkvb, vtb);
  attn_fwd<<<512, 512, 0, stream>>>(qkvb, vtb, attno);
  gemm1<1><<<256, 256, 0, stream>>>(attno, woutb, d_out, nullptr);
}

// Round 23
// 90.199 us; speedup vs baseline: 1.1275x; 1.1275x over previous
//
#include <hip/hip_runtime.h>

#define DIM_ 1024
#define HEADS_ 16
#define HD_ 64
#define T_ 2048
#define BATCH_ 2
#define QKVN_ 3072

typedef unsigned short u16;
typedef unsigned int u32;
typedef float f32x4 __attribute__((ext_vector_type(4)));
typedef float f32x16 __attribute__((ext_vector_type(16)));
typedef short s16x8 __attribute__((ext_vector_type(8)));
typedef unsigned short u16x4 __attribute__((ext_vector_type(4)));

__device__ __forceinline__ u16 f2bf(float f) {
  unsigned u = __float_as_uint(f);
  u += 0x7fffu + ((u >> 16) & 1u);
  return (u16)(u >> 16);
}

__device__ __forceinline__ float fexp2(float x) {
  float r;
  asm("v_exp_f32 %0, %1" : "=v"(r) : "v"(x));
  return r;
}

__device__ __forceinline__ float fmax3(float a, float b, float c) {
  float r;
  asm("v_max3_f32 %0, %1, %2, %3" : "=v"(r) : "v"(a), "v"(b), "v"(c));
  return r;
}

__device__ __forceinline__ u32 cvtpk(float a, float b) {
  u32 r;
  asm("v_cvt_pk_bf16_f32 %0, %1, %2" : "=v"(r) : "v"(a), "v"(b));
  return r;
}

// ---------------- fused fp32 -> bf16 conversion (x | w_qkv | w_out) ----------------
__global__ __launch_bounds__(256) void cvt_all(const float* __restrict__ x,
                                               const float* __restrict__ wqkv,
                                               const float* __restrict__ wout,
                                               u16* __restrict__ outbase) {
  int i = blockIdx.x * 256 + threadIdx.x;   // [0, 2097152)
  const float4* src;
  int off;
  if (i < 1048576) { src = (const float4*)x; off = i; }
  else if (i < 1835008) { src = (const float4*)wqkv; off = i - 1048576; }
  else { src = (const float4*)wout; off = i - 1835008; }
  float4 v = src[off];
  u16x4 o;
  o.x = f2bf(v.x); o.y = f2bf(v.y); o.z = f2bf(v.z); o.w = f2bf(v.w);
  reinterpret_cast<u16x4*>(outbase)[i] = o;
}

// ---------------- async global->LDS helper ----------------
__device__ __forceinline__ void gld_lds16(const void* g, void* l) {
  auto gp = (__attribute__((address_space(1))) char*)(unsigned long long)g;
  auto lp = (__attribute__((address_space(3))) char*)(unsigned int)(unsigned long long)l;
  __builtin_amdgcn_global_load_lds(gp, lp, 16, 0, 0);
}

// ---------------- GEMM, BK=64, double-buffered one-barrier pipeline (R21) ----------
// Layout (bytes): As buf b at [b*16384, +16K); Bs buf b at [32768 + b*16384, +16K).
// [barrier (drains prev prefetch) -> issue prefetch k+1 into buf^1 -> compute buf cur]
// 16 barriers/block; staging latency hidden under MFMA phase. XCD-chunked by mt.
template <int MODE>
__global__ __launch_bounds__(256) void gemm1(const u16* __restrict__ A,
                                             const u16* __restrict__ B,
                                             void* __restrict__ Cv,
                                             u16* __restrict__ vto) {
  constexpr int K = 1024;
  constexpr int NN = (MODE == 1) ? 1024 : QKVN_;
  constexpr int NT = (MODE == 1) ? 8 : 24;
  constexpr int CPX = (MODE == 1) ? 32 : 96;
  __shared__ __align__(16) u16 smem[32768];   // 64 KB
  char* const smb = (char*)smem;
  const int bid = blockIdx.x;
  const int wk = (bid & 7) * CPX + (bid >> 3);
  const int mt = wk / NT, nt = wk % NT;
  const int tid = threadIdx.x;
  const int lane = tid & 63;
  const int w = tid >> 6;
  const int wr = w >> 1, wc = w & 1;
  const int lrow = lane & 15, kg = lane >> 4;
  const u16* Ag = A + (size_t)(mt * 128) * K;
  const u16* Bg = B + (size_t)(nt * 128) * K;

  f32x4 acc[4][4];
#pragma unroll
  for (int i = 0; i < 4; ++i)
#pragma unroll
    for (int j = 0; j < 4; ++j) {
      f32x4 z = {0.f, 0.f, 0.f, 0.f};
      acc[i][j] = z;
    }

  const int srow = tid >> 3;
  const int scol = 8 * ((tid & 7) ^ ((tid >> 3) & 7));
  const int ldsw = (tid & ~63) * 16;

  int aoff[4][2], boff[4][2];
#pragma unroll
  for (int mf = 0; mf < 4; ++mf)
#pragma unroll
    for (int ks = 0; ks < 2; ++ks) {
      aoff[mf][ks] = (wr * 64 + mf * 16 + lrow) * 128 + (((ks * 4 + kg) ^ (lrow & 7)) << 4);
      boff[mf][ks] = (wc * 64 + mf * 16 + lrow) * 128 + (((ks * 4 + kg) ^ (lrow & 7)) << 4);
    }

  // prologue: stage K-tile 0 into buf 0
#pragma unroll
  for (int c = 0; c < 4; ++c) {
    gld_lds16(Ag + (size_t)(c * 32 + srow) * K + scol, smb + c * 4096 + ldsw);
    gld_lds16(Bg + (size_t)(c * 32 + srow) * K + scol, smb + 32768 + c * 4096 + ldsw);
  }

  int cur = 0;
  for (int k0 = 0; k0 < K; k0 += 64) {
    __syncthreads();   // drains in-flight prefetch (vmcnt) + publishes buf cur
    if (k0 + 64 < K) { // issue next-tile prefetch into buf^1; lands during compute
      const int nb = (cur ^ 1) * 16384;   // BYTE offset (tile = 16 KB)
#pragma unroll
      for (int c = 0; c < 4; ++c) {
        gld_lds16(Ag + (size_t)(c * 32 + srow) * K + k0 + 64 + scol,
                  smb + nb + c * 4096 + ldsw);
        gld_lds16(Bg + (size_t)(c * 32 + srow) * K + k0 + 64 + scol,
                  smb + 32768 + nb + c * 4096 + ldsw);
      }
    }
    const char* Ac = smb + cur * 16384;
    const char* Bc = smb + 32768 + cur * 16384;
#pragma unroll
    for (int ks = 0; ks < 2; ++ks) {
      s16x8 a[4], b[4];
#pragma unroll
      for (int mf = 0; mf < 4; ++mf)
        a[mf] = *(const s16x8*)(Ac + aoff[mf][ks]);
#pragma unroll
      for (int nf = 0; nf < 4; ++nf)
        b[nf] = *(const s16x8*)(Bc + boff[nf][ks]);
#pragma unroll
      for (int mf = 0; mf < 4; ++mf)
#pragma unroll
        for (int nf = 0; nf < 4; ++nf)
          acc[mf][nf] = __builtin_amdgcn_mfma_f32_16x16x32_bf16(a[mf], b[nf], acc[mf][nf], 0, 0, 0);
    }
    cur ^= 1;
  }

  if (MODE == 1) {
    float* C = (float*)Cv;
#pragma unroll
    for (int mf = 0; mf < 4; ++mf)
#pragma unroll
      for (int nf = 0; nf < 4; ++nf)
#pragma unroll
        for (int j = 0; j < 4; ++j) {
          int r = mt * 128 + wr * 64 + mf * 16 + 4 * kg + j;
          int c = nt * 128 + wc * 64 + nf * 16 + lrow;
          C[(size_t)r * NN + c] = acc[mf][nf][j];
        }
  } else if (nt < 16) {   // Q,K thirds: row-major bf16
    u16* qkvo = (u16*)Cv;
#pragma unroll
    for (int mf = 0; mf < 4; ++mf)
#pragma unroll
      for (int nf = 0; nf < 4; ++nf)
#pragma unroll
        for (int j = 0; j < 4; ++j) {
          int r = mt * 128 + wr * 64 + mf * 16 + 4 * kg + j;
          int c = nt * 128 + wc * 64 + nf * 16 + lrow;
          qkvo[(size_t)r * QKVN_ + c] = f2bf(acc[mf][nf][j]);
        }
  } else {                // V third: 2-pass LDS transpose -> coalesced vt stores
    const int c16 = tid >> 4, chunk = tid & 15;
    const int bb = mt >> 4;
    const int tb = (mt & 15) * 128 + chunk * 8;
#pragma unroll
    for (int p = 0; p < 2; ++p) {
      __syncthreads();
      if (wc == p) {
#pragma unroll
        for (int mf = 0; mf < 4; ++mf)
#pragma unroll
          for (int nf = 0; nf < 4; ++nf) {
            const int cl = nf * 16 + lrow;
            const int rl = wr * 64 + mf * 16 + 4 * kg;
            u16x4 pk;
            pk.x = f2bf(acc[mf][nf][0]); pk.y = f2bf(acc[mf][nf][1]);
            pk.z = f2bf(acc[mf][nf][2]); pk.w = f2bf(acc[mf][nf][3]);
            *(u16x4*)&smem[cl * 136 + rl] = pk;
          }
      }
      __syncthreads();
#pragma unroll
      for (int pp = 0; pp < 4; ++pp) {
        const int cl = pp * 16 + c16;
        const int cg = nt * 128 + p * 64 + cl;
        const int hV = (cg >> 6) & 15, d = cg & 63;
        const s16x8 v = *(const s16x8*)&smem[cl * 136 + chunk * 8];
        *(s16x8*)(vto + ((size_t)((bb * 16 + hV) * 64 + d)) * T_ + tb) = v;
      }
    }
  }
}

// ---------------- causal flash attention (paired q-tiles, XCD bh-clustered) ------------
// Best-measured configuration (R15/R19/R21) — unchanged.
__global__ __launch_bounds__(256, 2) void attn_fwd(const u16* __restrict__ qkv,
                                                   const u16* __restrict__ vt,
                                                   u16* __restrict__ o) {
  const int gid = blockIdx.x;
  const int gq = gid >> 3;
  const int bh = (gid & 7) * 4 + (gq >> 4);
  const int pr = gq & 15;              // 0..15
  const int b = bh >> 4, h = bh & 15;
  const int tid = threadIdx.x;
  const int lane = tid & 63;
  const int qw = (tid >> 6) & 1;       // q-subwave (32 rows)
  const int kvg = tid >> 7;            // kv parity
  const int l31 = lane & 31, hi = lane >> 5;

  // K: smem + buf*16384 + par*8192 ; V: +32768 same
  __shared__ __align__(16) char smem[65536];

  const int row_s = tid >> 3, slot_s = tid & 7;
  const u16* Kbase = qkv + (size_t)(b * T_) * QKVN_ + 1024 + h * 64;
  const u16* Vbase = vt + (size_t)(bh * 64) * T_;
  const u16* KgA = Kbase + (size_t)row_s * QKVN_ + slot_s * 8;
  const u16* KgB = KgA + (size_t)32 * QKVN_;
  const u16* VgA = Vbase + (size_t)row_s * T_ + slot_s * 8;
  const u16* VgB = VgA + (size_t)32 * T_;
  const int dstA = row_s * 128 + ((slot_s ^ (row_s & 7)) << 4);  // +4096 for chunk B

  const int rbyte = l31 * 128;
  const int xsw = l31 & 7;
  const float CEXP = 0.18033688011112042f;  // (1/8) * log2(e)

  for (int ph = 0; ph < 2; ++ph) {
    const int jt = (ph == 0) ? (31 - pr) : pr;
    const int nt = jt + 1;
    const int nrt = (nt + 1) >> 1;
    const int qrow0 = 64 * jt + 32 * qw;

    // Q fragments: lane (l31,hi) holds Q[qrow0+l31][16*ksl + 8*hi .. +8]
    s16x8 qf[4];
    {
      const u16* qp = qkv + (size_t)(b * T_ + qrow0 + l31) * QKVN_ + h * 64 + 8 * hi;
#pragma unroll
      for (int ksl = 0; ksl < 4; ++ksl)
        qf[ksl] = *(const s16x8*)(qp + 16 * ksl);
    }

    f32x16 o0v, o1v;
#pragma unroll
    for (int r = 0; r < 16; ++r) { o0v[r] = 0.f; o1v[r] = 0.f; }
    float mrun = -__builtin_inff(), lrun = 0.0f;

    __syncthreads();   // smem free (prev phase merge fully read)
    // prologue: stage tiles 0 (and 1) into buf 0
    *(s16x8*)(smem + dstA)                 = *(const s16x8*)KgA;
    *(s16x8*)(smem + 4096 + dstA)          = *(const s16x8*)KgB;
    *(s16x8*)(smem + 32768 + dstA)         = *(const s16x8*)VgA;
    *(s16x8*)(smem + 32768 + 4096 + dstA)  = *(const s16x8*)VgB;
    if (nt > 1) {
      *(s16x8*)(smem + 8192 + dstA)                = *(const s16x8*)(KgA + (size_t)64 * QKVN_);
      *(s16x8*)(smem + 8192 + 4096 + dstA)         = *(const s16x8*)(KgB + (size_t)64 * QKVN_);
      *(s16x8*)(smem + 32768 + 8192 + dstA)        = *(const s16x8*)(VgA + 64);
      *(s16x8*)(smem + 32768 + 8192 + 4096 + dstA) = *(const s16x8*)(VgB + 64);
    }

    int cur = 0;
    for (int r = 0; r < nrt; ++r) {
      const int t = 2 * r + kvg;
      const bool pe = (2 * r + 2 < nt), po = (2 * r + 3 < nt);
      s16x8 ke0, ke1, ve0, ve1, ko0, ko1, vo0, vo1;
      if (pe) {                         // issue next-round loads early
        const size_t kofs = (size_t)(2 * r + 2) * 64 * QKVN_;
        const int vofs = (2 * r + 2) * 64;
        ke0 = *(const s16x8*)(KgA + kofs);
        ke1 = *(const s16x8*)(KgB + kofs);
        ve0 = *(const s16x8*)(VgA + vofs);
        ve1 = *(const s16x8*)(VgB + vofs);
      }
      if (po) {
        const size_t kofs = (size_t)(2 * r + 3) * 64 * QKVN_;
        const int vofs = (2 * r + 3) * 64;
        ko0 = *(const s16x8*)(KgA + kofs);
        ko1 = *(const s16x8*)(KgB + kofs);
        vo0 = *(const s16x8*)(VgA + vofs);
        vo1 = *(const s16x8*)(VgB + vofs);
      }
      __syncthreads();

      if (t < nt) {
        const char* Kc = smem + cur * 16384 + kvg * 8192;
        const char* Vc = smem + 32768 + cur * 16384 + kvg * 8192;
        const bool isdiag = (t == nt - 1);
        const bool two = !(isdiag && qw == 0);

        // ---- QK^T (swapped): lane holds q = qrow0+l31 ----
        f32x16 s0v, s1v;
#pragma unroll
        for (int rr = 0; rr < 16; ++rr) { s0v[rr] = 0.f; s1v[rr] = 0.f; }
        __builtin_amdgcn_s_setprio(1);
#pragma unroll
        for (int ksl = 0; ksl < 4; ++ksl) {
          const s16x8 kf = *(const s16x8*)(Kc + rbyte + (((2 * ksl + hi) ^ xsw) << 4));
          s0v = __builtin_amdgcn_mfma_f32_32x32x16_bf16(kf, qf[ksl], s0v, 0, 0, 0);
        }
        if (two) {
#pragma unroll
          for (int ksl = 0; ksl < 4; ++ksl) {
            const s16x8 kf = *(const s16x8*)(Kc + 4096 + rbyte + (((2 * ksl + hi) ^ xsw) << 4));
            s1v = __builtin_amdgcn_mfma_f32_32x32x16_bf16(kf, qf[ksl], s1v, 0, 0, 0);
          }
        }
        __builtin_amdgcn_s_setprio(0);

        // ---- causal mask (diagonal tile only) ----
        if (isdiag) {
          const int thr = 32 * qw + l31;
#pragma unroll
          for (int rr = 0; rr < 16; ++rr) {
            const int kvl = 4 * hi + (rr & 3) + 8 * (rr >> 2);
            if (kvl > thr) s0v[rr] = -__builtin_inff();
            if (two && kvl + 32 > thr) s1v[rr] = -__builtin_inff();
          }
        }

        // ---- online softmax, per-lane (v_max3 tree) ----
        float mloc = fmax3(s0v[0], s0v[1], s0v[2]);
#pragma unroll
        for (int rr = 3; rr < 15; rr += 2) mloc = fmax3(mloc, s0v[rr], s0v[rr + 1]);
        mloc = fmaxf(mloc, s0v[15]);
        if (two) {
          mloc = fmax3(mloc, s1v[0], s1v[1]);
#pragma unroll
          for (int rr = 2; rr < 16; rr += 2) mloc = fmax3(mloc, s1v[rr], s1v[rr + 1]);
        }
        mloc = fmaxf(mloc, __shfl_xor(mloc, 32));

        const bool needfull = !((mloc - mrun) * CEXP <= 8.0f);
        if (__any(needfull)) {
          const float newm = fmaxf(mrun, mloc);
          const float sc = fexp2((mrun - newm) * CEXP);
          mrun = newm;
          lrun *= sc;
          o0v *= sc;
          o1v *= sc;
        }
        const float msc = mrun * CEXP;

        float rs = 0.0f;
        u32 pd0[8], pd1[8];
#pragma unroll
        for (int ri = 0; ri < 8; ++ri) {
          const float p0 = fexp2(__builtin_fmaf(s0v[2 * ri], CEXP, -msc));
          const float p1 = fexp2(__builtin_fmaf(s0v[2 * ri + 1], CEXP, -msc));
          rs += p0 + p1;
          pd0[ri] = cvtpk(p0, p1);
        }
        if (two) {
#pragma unroll
          for (int ri = 0; ri < 8; ++ri) {
            const float p0 = fexp2(__builtin_fmaf(s1v[2 * ri], CEXP, -msc));
            const float p1 = fexp2(__builtin_fmaf(s1v[2 * ri + 1], CEXP, -msc));
            rs += p0 + p1;
            pd1[ri] = cvtpk(p0, p1);
          }
        }
        rs += __shfl_xor(rs, 32);
        lrun += rs;

        // ---- PV: rebuild B-fragments in-register, accumulate O^T ----
        __builtin_amdgcn_s_setprio(1);
#pragma unroll
        for (int kk = 0; kk < 4; ++kk) {
          if (kk >= 2 && !two) break;
          u32 x0, y0, x1, y1;
          if (kk == 0)      { x0 = pd0[0]; y0 = pd0[2]; x1 = pd0[1]; y1 = pd0[3]; }
          else if (kk == 1) { x0 = pd0[4]; y0 = pd0[6]; x1 = pd0[5]; y1 = pd0[7]; }
          else if (kk == 2) { x0 = pd1[0]; y0 = pd1[2]; x1 = pd1[1]; y1 = pd1[3]; }
          else              { x0 = pd1[4]; y0 = pd1[6]; x1 = pd1[5]; y1 = pd1[7]; }
          asm volatile("v_permlane32_swap_b32 %0, %1" : "+v"(x0), "+v"(y0));
          asm volatile("v_permlane32_swap_b32 %0, %1" : "+v"(x1), "+v"(y1));
          u32 pw[4] = {x0, x1, y0, y1};
          const s16x8 pf = *(const s16x8*)pw;
          const s16x8 vf0 = *(const s16x8*)(Vc + rbyte + (((2 * kk + hi) ^ xsw) << 4));
          const s16x8 vf1 = *(const s16x8*)(Vc + 4096 + rbyte + (((2 * kk + hi) ^ xsw) << 4));
          o0v = __builtin_amdgcn_mfma_f32_32x32x16_bf16(vf0, pf, o0v, 0, 0, 0);
          o1v = __builtin_amdgcn_mfma_f32_32x32x16_bf16(vf1, pf, o1v, 0, 0, 0);
        }
        __builtin_amdgcn_s_setprio(0);
      }

      if (pe) {                         // write-late into the other buffer set
        const int nb = (cur ^ 1) * 16384;
        *(s16x8*)(smem + nb + dstA)                = ke0;
        *(s16x8*)(smem + nb + 4096 + dstA)         = ke1;
        *(s16x8*)(smem + 32768 + nb + dstA)        = ve0;
        *(s16x8*)(smem + 32768 + nb + 4096 + dstA) = ve1;
      }
      if (po) {
        const int nb = (cur ^ 1) * 16384 + 8192;
        *(s16x8*)(smem + nb + dstA)                = ko0;
        *(s16x8*)(smem + nb + 4096 + dstA)         = ko1;
        *(s16x8*)(smem + 32768 + nb + dstA)        = vo0;
        *(s16x8*)(smem + 32768 + nb + 4096 + dstA) = vo1;
      }
      cur ^= 1;
    }

    // ---- merge kv-split pair partials (reuse LDS), write O ----
    __syncthreads();
    float* Om = (float*)smem + qw * 2048;            // 32 x 64 f32 per qw
    float* Mf = (float*)(smem + 16384) + qw * 64;
    float* Lf = (float*)(smem + 16896) + qw * 64;
    if (kvg == 1) {
#pragma unroll
      for (int rr = 0; rr < 16; ++rr) {
        Om[rr * 64 + lane] = o0v[rr];
        Om[(16 + rr) * 64 + lane] = o1v[rr];
      }
      Mf[lane] = mrun;
      Lf[lane] = lrun;
    }
    __syncthreads();
    if (kvg == 0) {
      const float mA = Mf[lane];
      const float lA = Lf[lane];
      const float m2 = fmaxf(mrun, mA);
      const float sB = fexp2((mrun - m2) * CEXP);
      const float sA = fexp2((mA - m2) * CEXP);
      const float linv = 1.0f / (lrun * sB + lA * sA);
      u16* orow = o + (size_t)(b * T_ + qrow0 + l31) * DIM_ + h * 64;
#pragma unroll
      for (int ri = 0; ri < 8; ++ri) {
        const int dbase0 = 4 * hi + 8 * (ri >> 1) + 2 * (ri & 1);
        const float a0 = (o0v[2 * ri] * sB + Om[(2 * ri) * 64 + lane] * sA) * linv;
        const float a1 = (o0v[2 * ri + 1] * sB + Om[(2 * ri + 1) * 64 + lane] * sA) * linv;
        const float c0 = (o1v[2 * ri] * sB + Om[(16 + 2 * ri) * 64 + lane] * sA) * linv;
        const float c1 = (o1v[2 * ri + 1] * sB + Om[(16 + 2 * ri + 1) * 64 + lane] * sA) * linv;
        *(u32*)(orow + dbase0) = cvtpk(a0, a1);
        *(u32*)(orow + 32 + dbase0) = cvtpk(c0, c1);
      }
    }
  }
}

// ---------------- launch ----------------
extern "C" void kernel_launch(void* const* d_in, const int* in_sizes, int n_in,
                              void* d_out, int out_size, void* d_ws, size_t ws_size,
                              hipStream_t stream) {
  const float* x = (const float*)d_in[0];
  const float* w_qkv = (const float*)d_in[1];
  const float* w_out = (const float*)d_in[2];
  char* ws = (char*)d_ws;
  u16* xb    = (u16*)(ws + 0);          // 8,388,608
  u16* wqkvb = (u16*)(ws + 8388608);    // 6,291,456
  u16* woutb = (u16*)(ws + 14680064);   // 2,097,152
  u16* qkvb  = (u16*)(ws + 16777216);   // 25,165,824 (V third unused)
  u16* vtb   = (u16*)(ws + 41943040);   // 8,388,608
  u16* attno = (u16*)(ws + 50331648);   // 8,388,608

  cvt_all<<<8192, 256, 0, stream>>>(x, w_qkv, w_out, xb);
  gemm1<2><<<768, 256, 0, stream>>>(xb, wqkvb, qkvb, vtb);
  attn_fwd<<<512, 256, 0, stream>>>(qkvb, vtb, attno);
  gemm1<1><<<256, 256, 0, stream>>>(attno, woutb, d_out, nullptr);
}